// Round 7
// baseline (261.486 us; speedup 1.0000x reference)
//
#include <hip/hip_runtime.h>
#include <math.h>

typedef _Float16 half_t;
typedef _Float16 half8 __attribute__((ext_vector_type(8)));
typedef _Float16 half4_t __attribute__((ext_vector_type(4)));
typedef _Float16 half2_t __attribute__((ext_vector_type(2)));
typedef float floatx4 __attribute__((ext_vector_type(4)));

#define M_TOK 512
#define N_DIM 2048
#define D_HEAD 128
#define H_HEADS 16
#define L_CACHE 4096
#define THREE_N 6144
#define NCHUNK 16
#define LCHUNK 256

// ---------------------------------------------------------------------------
// Kernel 1: merged prep. Regions by blockIdx.x:
//   [0,1024)     convert X fp32 -> X16 fp16
//   [1024,3072)  transpose cache_V [H,L,D] fp32 -> V16T [H,D,L] fp16
//                (128l x 32d tiles: 256B-contiguous output rows)
//   [3072,6144)  transpose W [K,3N] fp32 -> W16T [3N,K] fp16
//                (128k x 32n tiles: 256B-contiguous output rows)
// K is NOT converted: attn reads cache_K fp32 directly (no transpose needed).
// ---------------------------------------------------------------------------
__global__ __launch_bounds__(256) void prep_kernel(const float* __restrict__ cV,
                                                   const float* __restrict__ W,
                                                   const float* __restrict__ X,
                                                   half_t* __restrict__ V16T,
                                                   half_t* __restrict__ W16T,
                                                   half_t* __restrict__ X16) {
    __shared__ half_t tile[128 * 36];
    int b = blockIdx.x;
    int t = threadIdx.x;

    if (b < 1024) {  // convert X
        size_t i = ((size_t)b * 256 + t) * 4;
        float4 v = *(const float4*)(X + i);
        half4_t h = {(half_t)v.x, (half_t)v.y, (half_t)v.z, (half_t)v.w};
        *(half4_t*)(X16 + i) = h;
        return;
    }
    b -= 1024;
    if (b < 2048) {  // transpose V: 128(l) x 32(d) tile
        int h = b >> 7;
        int rem = b & 127;
        int l0 = (rem >> 2) * 128, d0 = (rem & 3) * 32;
        {
            int row = t >> 1, q = (t & 1) * 16;
            const float* src = cV + ((size_t)h * L_CACHE + l0 + row) * D_HEAD + d0 + q;
#pragma unroll
            for (int i = 0; i < 4; ++i) {
                float4 v = *(const float4*)(src + 4 * i);
                half4_t hv = {(half_t)v.x, (half_t)v.y, (half_t)v.z, (half_t)v.w};
                *(half4_t*)&tile[row * 36 + q + 4 * i] = hv;
            }
        }
        __syncthreads();
        {
            int drow = t >> 3, seg = (t & 7) * 16;
#pragma unroll
            for (int j = 0; j < 2; ++j) {
                half8 o;
#pragma unroll
                for (int kk = 0; kk < 8; ++kk)
                    o[kk] = tile[(seg + j * 8 + kk) * 36 + drow];
                *(half8*)(V16T + ((size_t)h * D_HEAD + d0 + drow) * L_CACHE + l0 + seg + j * 8) = o;
            }
        }
        return;
    }
    b -= 2048;
    {  // transpose W: 128(k) x 32(n) tile, b in [0,3072)
        int kt = b / 192, nt = b % 192;
        int k0 = kt * 128, n0 = nt * 32;
        {
            int row = t >> 1, q = (t & 1) * 16;
            const float* src = W + (size_t)(k0 + row) * THREE_N + n0 + q;
#pragma unroll
            for (int i = 0; i < 4; ++i) {
                float4 v = *(const float4*)(src + 4 * i);
                half4_t hv = {(half_t)v.x, (half_t)v.y, (half_t)v.z, (half_t)v.w};
                *(half4_t*)&tile[row * 36 + q + 4 * i] = hv;
            }
        }
        __syncthreads();
        {
            int nrow = t >> 3, seg = (t & 7) * 16;
#pragma unroll
            for (int j = 0; j < 2; ++j) {
                half8 o;
#pragma unroll
                for (int kk = 0; kk < 8; ++kk)
                    o[kk] = tile[(seg + j * 8 + kk) * 36 + nrow];
                *(half8*)(W16T + (size_t)(n0 + nrow) * N_DIM + k0 + seg + j * 8) = o;
            }
        }
    }
}

// ---------------------------------------------------------------------------
// Kernel 2: fused GEMM + RMS-norm + scatter.
// Tile = X16[64m x 2048] @ W16T[128n x 2048]^T. bx 0..15 q-head -> Q16 fp16,
// 16..31 k-head -> normalized fp32 rows written INTO cache_K at P..P+M,
// 32..47 v-head -> V16T columns via LDS transpose.
// ---------------------------------------------------------------------------
__global__ __launch_bounds__(256) void gemm_fused_kernel(const half_t* __restrict__ X16,
                                                         const half_t* __restrict__ W16T,
                                                         const int* __restrict__ Pp,
                                                         half_t* __restrict__ Q16,
                                                         float* __restrict__ cacheK,
                                                         half_t* __restrict__ V16T) {
    __shared__ half_t smem[64 * 72 + 128 * 72];  // As | Bs ; Vt aliases front
    __shared__ float ssbuf[4][32];
    half_t* As = smem;
    half_t* Bs = smem + 64 * 72;
    half_t* Vt = smem;  // epilogue only (after barrier)
    const int t = threadIdx.x;
    const int wid = t >> 6, lane = t & 63;
    const int quad = lane >> 4, ln = lane & 15;
    const int bx = blockIdx.x, by = blockIdx.y;
    const int m0 = by * 64, n0 = bx * 128;
    const int wm = (wid >> 1) * 32, wn = (wid & 1) * 64;

    floatx4 acc[2][4] = {};

    const int ar = t >> 3, ag = (t & 7) * 8;
    const int br = t >> 3, bg = (t & 7) * 8;

    for (int k0 = 0; k0 < N_DIM; k0 += 64) {
        __syncthreads();
#pragma unroll
        for (int p = 0; p < 2; ++p) {
            int r = ar + p * 32;
            *(half8*)&As[r * 72 + ag] =
                *(const half8*)(X16 + (size_t)(m0 + r) * N_DIM + k0 + ag);
        }
#pragma unroll
        for (int p = 0; p < 4; ++p) {
            int r = br + p * 32;
            *(half8*)&Bs[r * 72 + bg] =
                *(const half8*)(W16T + (size_t)(n0 + r) * N_DIM + k0 + bg);
        }
        __syncthreads();
#pragma unroll
        for (int kt = 0; kt < 2; ++kt) {
            half8 a[2], b[4];
#pragma unroll
            for (int i = 0; i < 2; ++i)
                a[i] = *(half8*)&As[(wm + i * 16 + ln) * 72 + kt * 32 + quad * 8];
#pragma unroll
            for (int j = 0; j < 4; ++j)
                b[j] = *(half8*)&Bs[(wn + j * 16 + ln) * 72 + kt * 32 + quad * 8];
#pragma unroll
            for (int i = 0; i < 2; ++i)
#pragma unroll
                for (int j = 0; j < 4; ++j)
                    acc[i][j] = __builtin_amdgcn_mfma_f32_16x16x32_f16(a[i], b[j], acc[i][j], 0, 0, 0);
        }
    }

    const int seg = bx >> 4, h = bx & 15;
    const int P = *Pp;

    if (seg < 2) {  // q or k: RMS-norm then write (block-uniform branch)
        float ss[2][4], scale[2][4];
#pragma unroll
        for (int i = 0; i < 2; ++i)
#pragma unroll
            for (int r = 0; r < 4; ++r) {
                float s = 0.f;
#pragma unroll
                for (int j = 0; j < 4; ++j) s += acc[i][j][r] * acc[i][j][r];
#pragma unroll
                for (int msk = 1; msk < 16; msk <<= 1) s += __shfl_xor(s, msk, 64);
                ss[i][r] = s;
            }
        if (ln == 0) {
#pragma unroll
            for (int i = 0; i < 2; ++i)
#pragma unroll
                for (int r = 0; r < 4; ++r)
                    ssbuf[wid][i * 16 + quad * 4 + r] = ss[i][r];
        }
        __syncthreads();
#pragma unroll
        for (int i = 0; i < 2; ++i)
#pragma unroll
            for (int r = 0; r < 4; ++r)
                scale[i][r] =
                    rsqrtf((ss[i][r] + ssbuf[wid ^ 1][i * 16 + quad * 4 + r]) * (1.0f / 128.0f));
#pragma unroll
        for (int i = 0; i < 2; ++i) {
            int mbase = m0 + wm + i * 16 + quad * 4;
#pragma unroll
            for (int j = 0; j < 4; ++j) {
                int col = wn + j * 16 + ln;
#pragma unroll
                for (int r = 0; r < 4; ++r) {
                    int m = mbase + r;
                    float v = acc[i][j][r] * scale[i][r];
                    if (seg == 0)
                        Q16[((size_t)h * M_TOK + m) * D_HEAD + col] = (half_t)v;
                    else
                        cacheK[((size_t)h * L_CACHE + P + m) * D_HEAD + col] = v;
                }
            }
        }
    } else {  // v: transpose via LDS (aliases As/Bs), write V^T columns
        __syncthreads();
#pragma unroll
        for (int i = 0; i < 2; ++i) {
            int mbase = wm + i * 16 + quad * 4;
#pragma unroll
            for (int j = 0; j < 4; ++j) {
                int d = wn + j * 16 + ln;
#pragma unroll
                for (int r = 0; r < 4; ++r)
                    Vt[d * 72 + mbase + r] = (half_t)acc[i][j][r];
            }
        }
        __syncthreads();
#pragma unroll
        for (int p = 0; p < 4; ++p) {
            int s = p * 256 + t;
            int d = s >> 3, sg = s & 7;
            *(half8*)(V16T + ((size_t)h * D_HEAD + d) * L_CACHE + P + m0 + sg * 8) =
                *(half8*)&Vt[d * 72 + sg * 8];
        }
    }
}

// ---------------------------------------------------------------------------
// Kernel 3: flash attention partial over L-chunk of 256. 1D grid of 1024.
// Swizzle v2: flat = g*32 + mb*8 + slot, pair(c,h) = g*8+slot. The 4 mb-blocks
// of one (h,c) have ids == mod 8 (same XCD) AND sit in one 32-block dispatch
// window (co-resident) -> concurrent L2 sharing of the K/V tile, ~0.5MB/XCD.
// K is staged fp32 (cache_K direct, incl. gemm-written rows) -> fp16 LDS.
// Unnormalized fp16 partial O [c][h][m][d] + (m,l) stats.
// ---------------------------------------------------------------------------
__global__ __launch_bounds__(256) void attn_partial_kernel(const half_t* __restrict__ Q16,
                                                           const float* __restrict__ cacheK,
                                                           const half_t* __restrict__ V16T,
                                                           half_t* __restrict__ Opart,
                                                           float* __restrict__ mstat,
                                                           float* __restrict__ lstat) {
    __shared__ half_t Ks[64 * 136];
    __shared__ half_t Vs[128 * 72];
    __shared__ half_t Ps[4 * 16 * 72];
    const int t = threadIdx.x, w = t >> 6, lane = t & 63;
    const int quad = lane >> 4, ln = lane & 15;
    const int f = blockIdx.x;
    const int pair = (f >> 5) * 8 + (f & 7);
    const int c = pair >> 4, h = pair & 15;
    const int mb = ((f >> 3) & 3) * 128;
    const half_t* Qh = Q16 + (size_t)h * M_TOK * D_HEAD;
    const float* Kh = cacheK + (size_t)h * L_CACHE * D_HEAD;
    const half_t* Vh = V16T + (size_t)h * D_HEAD * L_CACHE;

    half8 qf[2][4];
#pragma unroll
    for (int s = 0; s < 2; ++s) {
        int m0 = mb + s * 64 + w * 16;
#pragma unroll
        for (int dt = 0; dt < 4; ++dt)
            qf[s][dt] = *(const half8*)(Qh + (size_t)(m0 + ln) * D_HEAD + dt * 32 + quad * 8);
    }

    floatx4 oacc[2][8] = {};
    float mrow[2][4], lrow[2][4];
#pragma unroll
    for (int s = 0; s < 2; ++s)
#pragma unroll
        for (int r = 0; r < 4; ++r) { mrow[s][r] = -INFINITY; lrow[s][r] = 0.f; }

    half_t* Pw = Ps + w * (16 * 72);

    for (int l0 = c * LCHUNK; l0 < (c + 1) * LCHUNK; l0 += 64) {
        __syncthreads();
        {   // K tile 64l x 128d, fp32 -> fp16
            int lr = t >> 4, ch = (t & 15) * 8;
#pragma unroll
            for (int p = 0; p < 4; ++p, lr += 16) {
                const float* src = Kh + (size_t)(l0 + lr) * D_HEAD + ch;
                float4 a = *(const float4*)src;
                float4 bq = *(const float4*)(src + 4);
                half8 hv = {(half_t)a.x, (half_t)a.y, (half_t)a.z, (half_t)a.w,
                            (half_t)bq.x, (half_t)bq.y, (half_t)bq.z, (half_t)bq.w};
                *(half8*)&Ks[lr * 136 + ch] = hv;
            }
        }
        {   // V tile 128d x 64l, fp16
            int dr = t >> 3, ch = t & 7;
#pragma unroll
            for (int p = 0; p < 4; ++p, dr += 32)
                *(half8*)&Vs[dr * 72 + ch * 8] =
                    *(const half8*)(Vh + (size_t)dr * L_CACHE + l0 + ch * 8);
        }
        __syncthreads();

#pragma unroll
        for (int s = 0; s < 2; ++s) {
            floatx4 sacc[4] = {};
#pragma unroll
            for (int nt = 0; nt < 4; ++nt)
#pragma unroll
                for (int dt = 0; dt < 4; ++dt) {
                    half8 b = *(half8*)&Ks[(nt * 16 + ln) * 136 + dt * 32 + quad * 8];
                    sacc[nt] = __builtin_amdgcn_mfma_f32_16x16x32_f16(qf[s][dt], b, sacc[nt], 0, 0, 0);
                }

            float alpha[4];
#pragma unroll
            for (int r = 0; r < 4; ++r) {
                float mx = fmaxf(fmaxf(sacc[0][r], sacc[1][r]), fmaxf(sacc[2][r], sacc[3][r]));
#pragma unroll
                for (int msk = 8; msk; msk >>= 1) mx = fmaxf(mx, __shfl_xor(mx, msk, 16));
                float mnew = fmaxf(mrow[s][r], mx);
                alpha[r] = __expf(mrow[s][r] - mnew);
                mrow[s][r] = mnew;
                float psum = 0.f;
#pragma unroll
                for (int nt = 0; nt < 4; ++nt) {
                    float p = __expf(sacc[nt][r] - mnew);
                    sacc[nt][r] = p;
                    psum += p;
                }
#pragma unroll
                for (int msk = 8; msk; msk >>= 1) psum += __shfl_xor(psum, msk, 16);
                lrow[s][r] = lrow[s][r] * alpha[r] + psum;
            }

#pragma unroll
            for (int nt = 0; nt < 4; ++nt)
#pragma unroll
                for (int r = 0; r < 4; ++r)
                    Pw[(quad * 4 + r) * 72 + nt * 16 + ln] = (half_t)sacc[nt][r];

#pragma unroll
            for (int nt8 = 0; nt8 < 8; ++nt8)
#pragma unroll
                for (int r = 0; r < 4; ++r)
                    oacc[s][nt8][r] *= alpha[r];

#pragma unroll
            for (int kt = 0; kt < 2; ++kt) {
                half8 a = *(half8*)&Pw[ln * 72 + kt * 32 + quad * 8];
#pragma unroll
                for (int nt8 = 0; nt8 < 8; ++nt8) {
                    half8 b = *(half8*)&Vs[(nt8 * 16 + ln) * 72 + kt * 32 + quad * 8];
                    oacc[s][nt8] = __builtin_amdgcn_mfma_f32_16x16x32_f16(a, b, oacc[s][nt8], 0, 0, 0);
                }
            }
        }
    }

    // Opart [c][h][m][d] (coalesced block-contiguous region); stats [c][h][m]
    half_t* Oc = Opart + ((size_t)(c * H_HEADS + h) * M_TOK) * D_HEAD;
    float* ms = mstat + (size_t)(c * H_HEADS + h) * M_TOK;
    float* ls = lstat + (size_t)(c * H_HEADS + h) * M_TOK;
#pragma unroll
    for (int s = 0; s < 2; ++s) {
        int m0 = mb + s * 64 + w * 16;
#pragma unroll
        for (int nt8 = 0; nt8 < 8; ++nt8) {
            int col = nt8 * 16 + ln;
#pragma unroll
            for (int r = 0; r < 4; ++r)
                Oc[(size_t)(m0 + quad * 4 + r) * D_HEAD + col] = (half_t)oacc[s][nt8][r];
        }
        if (ln == 0) {
#pragma unroll
            for (int r = 0; r < 4; ++r) {
                ms[m0 + quad * 4 + r] = mrow[s][r];
                ls[m0 + quad * 4 + r] = lrow[s][r];
            }
        }
    }
}

// ---------------------------------------------------------------------------
// Kernel 4: combine NCHUNK fp16 partials. One wave per (h,m) row.
// ---------------------------------------------------------------------------
__global__ __launch_bounds__(256) void combine_kernel(const half_t* __restrict__ Opart,
                                                      const float* __restrict__ mstat,
                                                      const float* __restrict__ lstat,
                                                      float* __restrict__ out) {
    int gw = blockIdx.x * 4 + (threadIdx.x >> 6);
    int lane = threadIdx.x & 63;
    int h = gw >> 9, m = gw & 511;
    int d = lane * 2;

    float ms[NCHUNK];
    float mg = -INFINITY;
#pragma unroll
    for (int c = 0; c < NCHUNK; ++c) {
        ms[c] = mstat[((c * H_HEADS + h) << 9) + m];
        mg = fmaxf(mg, ms[c]);
    }
    float denom = 0.f, o0 = 0.f, o1 = 0.f;
#pragma unroll
    for (int c = 0; c < NCHUNK; ++c) {
        float e = __expf(ms[c] - mg);
        denom += lstat[((c * H_HEADS + h) << 9) + m] * e;
        const half_t* Oc = Opart + (((size_t)(c * H_HEADS + h) << 9) + m) * D_HEAD + d;
        half2_t v = *(const half2_t*)Oc;
        o0 += (float)v.x * e;
        o1 += (float)v.y * e;
    }
    float inv = 1.0f / denom;
    float* op = out + (size_t)m * N_DIM + h * D_HEAD + d;
    op[0] = o0 * inv;
    op[1] = o1 * inv;
}

// ---------------------------------------------------------------------------
extern "C" void kernel_launch(void* const* d_in, const int* in_sizes, int n_in,
                              void* d_out, int out_size, void* d_ws, size_t ws_size,
                              hipStream_t stream) {
    const float* X = (const float*)d_in[0];
    const float* W = (const float*)d_in[1];
    float* cK = (float*)d_in[2];  // written at rows P..P+M by gemm (harness
                                  // restores pristine inputs each launch)
    const float* cV = (const float*)d_in[3];
    const int* Pp = (const int*)d_in[4];
    float* out = (float*)d_out;

    char* ws = (char*)d_ws;
    // workspace layout (bytes):
    //   Q16    @ 0           (2,097,152)
    //   V16T   @ 2,097,152   (16,777,216)
    //   X16    @ 18,874,368  (2,097,152)
    //   W16T   @ 20,971,520  (25,165,824)  [dead after gemm_fused]
    //   Opart16@ 20,971,520  (33,554,432)  [overlays W16T]
    //   mstat  @ 54,525,952  (524,288)
    //   lstat  @ 55,050,240  (524,288)
    //   total 55,574,528
    half_t* Q16 = (half_t*)(ws + 0);
    half_t* V16T = (half_t*)(ws + 2097152);
    half_t* X16 = (half_t*)(ws + 18874368);
    half_t* W16T = (half_t*)(ws + 20971520);
    half_t* Opart = (half_t*)(ws + 20971520);
    float* mstat = (float*)(ws + 54525952);
    float* lstat = (float*)(ws + 55050240);

    prep_kernel<<<6144, 256, 0, stream>>>(cV, W, X, V16T, W16T, X16);
    gemm_fused_kernel<<<dim3(48, 8), 256, 0, stream>>>(X16, W16T, Pp, Q16, cK, V16T);
    attn_partial_kernel<<<1024, 256, 0, stream>>>(Q16, cK, V16T, Opart, mstat, lstat);
    combine_kernel<<<2048, 256, 0, stream>>>(Opart, mstat, lstat, out);
}

// Round 8
// 254.750 us; speedup vs baseline: 1.0264x; 1.0264x over previous
//
#include <hip/hip_runtime.h>
#include <math.h>

typedef _Float16 half_t;
typedef _Float16 half8 __attribute__((ext_vector_type(8)));
typedef _Float16 half4_t __attribute__((ext_vector_type(4)));
typedef _Float16 half2_t __attribute__((ext_vector_type(2)));
typedef float floatx4 __attribute__((ext_vector_type(4)));

#define M_TOK 512
#define N_DIM 2048
#define D_HEAD 128
#define H_HEADS 16
#define L_CACHE 4096
#define THREE_N 6144
#define NCHUNK 16
#define LCHUNK 256

// ---------------------------------------------------------------------------
// Kernel 1: merged prep. Regions by blockIdx.x:
//   [0,8192)        convert cache_K fp32 -> K16 fp16 [H,L,D]
//   [8192,9216)     convert X fp32 -> X16 fp16
//   [9216,11264)    transpose cache_V [H,L,D] fp32 -> V16T [H,D,L] fp16
//                   (128l x 32d tiles, 256B-contiguous writes)
//   [11264,14336)   transpose W [K,3N] fp32 -> W16T [3N,K] fp16
//                   (128k x 32n tiles, 256B-contiguous writes)
// ---------------------------------------------------------------------------
__global__ __launch_bounds__(256) void prep_kernel(const float* __restrict__ cK,
                                                   const float* __restrict__ cV,
                                                   const float* __restrict__ W,
                                                   const float* __restrict__ X,
                                                   half_t* __restrict__ K16,
                                                   half_t* __restrict__ V16T,
                                                   half_t* __restrict__ W16T,
                                                   half_t* __restrict__ X16) {
    __shared__ half_t tile[128 * 36];
    int b = blockIdx.x;
    int t = threadIdx.x;

    if (b < 8192) {  // convert K
        size_t i = ((size_t)b * 256 + t) * 4;
        float4 v = *(const float4*)(cK + i);
        half4_t h = {(half_t)v.x, (half_t)v.y, (half_t)v.z, (half_t)v.w};
        *(half4_t*)(K16 + i) = h;
        return;
    }
    b -= 8192;
    if (b < 1024) {  // convert X
        size_t i = ((size_t)b * 256 + t) * 4;
        float4 v = *(const float4*)(X + i);
        half4_t h = {(half_t)v.x, (half_t)v.y, (half_t)v.z, (half_t)v.w};
        *(half4_t*)(X16 + i) = h;
        return;
    }
    b -= 1024;
    if (b < 2048) {  // transpose V: 128(l) x 32(d) tile
        int h = b >> 7;
        int rem = b & 127;
        int l0 = (rem >> 2) * 128, d0 = (rem & 3) * 32;
        {
            int row = t >> 1, q = (t & 1) * 16;
            const float* src = cV + ((size_t)h * L_CACHE + l0 + row) * D_HEAD + d0 + q;
#pragma unroll
            for (int i = 0; i < 4; ++i) {
                float4 v = *(const float4*)(src + 4 * i);
                half4_t hv = {(half_t)v.x, (half_t)v.y, (half_t)v.z, (half_t)v.w};
                *(half4_t*)&tile[row * 36 + q + 4 * i] = hv;
            }
        }
        __syncthreads();
        {
            int drow = t >> 3, seg = (t & 7) * 16;
#pragma unroll
            for (int j = 0; j < 2; ++j) {
                half8 o;
#pragma unroll
                for (int kk = 0; kk < 8; ++kk)
                    o[kk] = tile[(seg + j * 8 + kk) * 36 + drow];
                *(half8*)(V16T + ((size_t)h * D_HEAD + d0 + drow) * L_CACHE + l0 + seg + j * 8) = o;
            }
        }
        return;
    }
    b -= 2048;
    {  // transpose W: 128(k) x 32(n) tile, b in [0,3072)
        int kt = b / 192, nt = b % 192;
        int k0 = kt * 128, n0 = nt * 32;
        {
            int row = t >> 1, q = (t & 1) * 16;
            const float* src = W + (size_t)(k0 + row) * THREE_N + n0 + q;
#pragma unroll
            for (int i = 0; i < 4; ++i) {
                float4 v = *(const float4*)(src + 4 * i);
                half4_t hv = {(half_t)v.x, (half_t)v.y, (half_t)v.z, (half_t)v.w};
                *(half4_t*)&tile[row * 36 + q + 4 * i] = hv;
            }
        }
        __syncthreads();
        {
            int nrow = t >> 3, seg = (t & 7) * 16;
#pragma unroll
            for (int j = 0; j < 2; ++j) {
                half8 o;
#pragma unroll
                for (int kk = 0; kk < 8; ++kk)
                    o[kk] = tile[(seg + j * 8 + kk) * 36 + nrow];
                *(half8*)(W16T + (size_t)(n0 + nrow) * N_DIM + k0 + seg + j * 8) = o;
            }
        }
    }
}

// ---------------------------------------------------------------------------
// Kernel 2: fused GEMM + RMS-norm + scatter.
// Tile = X16[64m x 2048] @ W16T[128n x 2048]^T. bx 0..15 q-head -> Q16 fp16,
// 16..31 k-head -> normalized fp16 rows into K16 at P..P+M,
// 32..47 v-head -> V16T columns via LDS transpose (Vt aliases As/Bs).
// ---------------------------------------------------------------------------
__global__ __launch_bounds__(256) void gemm_fused_kernel(const half_t* __restrict__ X16,
                                                         const half_t* __restrict__ W16T,
                                                         const int* __restrict__ Pp,
                                                         half_t* __restrict__ Q16,
                                                         half_t* __restrict__ K16,
                                                         half_t* __restrict__ V16T) {
    __shared__ half_t smem[64 * 72 + 128 * 72];  // As | Bs ; Vt aliases front
    __shared__ float ssbuf[4][32];
    half_t* As = smem;
    half_t* Bs = smem + 64 * 72;
    half_t* Vt = smem;  // epilogue only (after barrier)
    const int t = threadIdx.x;
    const int wid = t >> 6, lane = t & 63;
    const int quad = lane >> 4, ln = lane & 15;
    const int bx = blockIdx.x, by = blockIdx.y;
    const int m0 = by * 64, n0 = bx * 128;
    const int wm = (wid >> 1) * 32, wn = (wid & 1) * 64;

    floatx4 acc[2][4] = {};

    const int ar = t >> 3, ag = (t & 7) * 8;
    const int br = t >> 3, bg = (t & 7) * 8;

    for (int k0 = 0; k0 < N_DIM; k0 += 64) {
        __syncthreads();
#pragma unroll
        for (int p = 0; p < 2; ++p) {
            int r = ar + p * 32;
            *(half8*)&As[r * 72 + ag] =
                *(const half8*)(X16 + (size_t)(m0 + r) * N_DIM + k0 + ag);
        }
#pragma unroll
        for (int p = 0; p < 4; ++p) {
            int r = br + p * 32;
            *(half8*)&Bs[r * 72 + bg] =
                *(const half8*)(W16T + (size_t)(n0 + r) * N_DIM + k0 + bg);
        }
        __syncthreads();
#pragma unroll
        for (int kt = 0; kt < 2; ++kt) {
            half8 a[2], b[4];
#pragma unroll
            for (int i = 0; i < 2; ++i)
                a[i] = *(half8*)&As[(wm + i * 16 + ln) * 72 + kt * 32 + quad * 8];
#pragma unroll
            for (int j = 0; j < 4; ++j)
                b[j] = *(half8*)&Bs[(wn + j * 16 + ln) * 72 + kt * 32 + quad * 8];
#pragma unroll
            for (int i = 0; i < 2; ++i)
#pragma unroll
                for (int j = 0; j < 4; ++j)
                    acc[i][j] = __builtin_amdgcn_mfma_f32_16x16x32_f16(a[i], b[j], acc[i][j], 0, 0, 0);
        }
    }

    const int seg = bx >> 4, h = bx & 15;
    const int P = *Pp;

    if (seg < 2) {  // q or k: RMS-norm then write (block-uniform branch)
        float ss[2][4], scale[2][4];
#pragma unroll
        for (int i = 0; i < 2; ++i)
#pragma unroll
            for (int r = 0; r < 4; ++r) {
                float s = 0.f;
#pragma unroll
                for (int j = 0; j < 4; ++j) s += acc[i][j][r] * acc[i][j][r];
#pragma unroll
                for (int msk = 1; msk < 16; msk <<= 1) s += __shfl_xor(s, msk, 64);
                ss[i][r] = s;
            }
        if (ln == 0) {
#pragma unroll
            for (int i = 0; i < 2; ++i)
#pragma unroll
                for (int r = 0; r < 4; ++r)
                    ssbuf[wid][i * 16 + quad * 4 + r] = ss[i][r];
        }
        __syncthreads();
#pragma unroll
        for (int i = 0; i < 2; ++i)
#pragma unroll
            for (int r = 0; r < 4; ++r)
                scale[i][r] =
                    rsqrtf((ss[i][r] + ssbuf[wid ^ 1][i * 16 + quad * 4 + r]) * (1.0f / 128.0f));
#pragma unroll
        for (int i = 0; i < 2; ++i) {
            int mbase = m0 + wm + i * 16 + quad * 4;
#pragma unroll
            for (int j = 0; j < 4; ++j) {
                int col = wn + j * 16 + ln;
#pragma unroll
                for (int r = 0; r < 4; ++r) {
                    int m = mbase + r;
                    half_t val = (half_t)(acc[i][j][r] * scale[i][r]);
                    if (seg == 0)
                        Q16[((size_t)h * M_TOK + m) * D_HEAD + col] = val;
                    else
                        K16[((size_t)h * L_CACHE + P + m) * D_HEAD + col] = val;
                }
            }
        }
    } else {  // v: transpose via LDS (aliases As/Bs), write V^T columns
        __syncthreads();
#pragma unroll
        for (int i = 0; i < 2; ++i) {
            int mbase = wm + i * 16 + quad * 4;
#pragma unroll
            for (int j = 0; j < 4; ++j) {
                int d = wn + j * 16 + ln;
#pragma unroll
                for (int r = 0; r < 4; ++r)
                    Vt[d * 72 + mbase + r] = (half_t)acc[i][j][r];
            }
        }
        __syncthreads();
#pragma unroll
        for (int p = 0; p < 4; ++p) {
            int s = p * 256 + t;
            int d = s >> 3, sg = s & 7;
            *(half8*)(V16T + ((size_t)h * D_HEAD + d) * L_CACHE + P + m0 + sg * 8) =
                *(half8*)&Vt[d * 72 + sg * 8];
        }
    }
}

// ---------------------------------------------------------------------------
// Kernel 3: flash attention partial over L-chunk of 256. 1D grid of 1024.
// Swizzle v2 (kept from R7 — FETCH 25.7MB proven): flat = g*32 + mb*8 + slot;
// the 4 mb-blocks of one (h,c) share an XCD AND a 32-block dispatch window.
// LDS diet: K-tile and V-tile share ONE buffer (K-phase then V-phase per
// l-iter, 2 extra barriers) -> 27.6 KB -> 5 blocks/CU, whole grid co-resident.
// Ks fragments shared across both m-strips (loop reorder halves Ks reads).
// ---------------------------------------------------------------------------
__global__ __launch_bounds__(256) void attn_partial_kernel(const half_t* __restrict__ Q16,
                                                           const half_t* __restrict__ K16,
                                                           const half_t* __restrict__ V16T,
                                                           half_t* __restrict__ Opart,
                                                           float* __restrict__ mstat,
                                                           float* __restrict__ lstat) {
    __shared__ half_t KV[9216];         // K-phase: [l][d] 64x136; V-phase: [d][l] 128x72
    __shared__ half_t Ps[4 * 16 * 72];  // per-wave P tile
    const int t = threadIdx.x, w = t >> 6, lane = t & 63;
    const int quad = lane >> 4, ln = lane & 15;
    const int f = blockIdx.x;
    const int pair = (f >> 5) * 8 + (f & 7);
    const int c = pair >> 4, h = pair & 15;
    const int mb = ((f >> 3) & 3) * 128;
    const half_t* Qh = Q16 + (size_t)h * M_TOK * D_HEAD;
    const half_t* Kh = K16 + (size_t)h * L_CACHE * D_HEAD;
    const half_t* Vh = V16T + (size_t)h * D_HEAD * L_CACHE;

    half8 qf[2][4];
#pragma unroll
    for (int s = 0; s < 2; ++s) {
        int m0 = mb + s * 64 + w * 16;
#pragma unroll
        for (int dt = 0; dt < 4; ++dt)
            qf[s][dt] = *(const half8*)(Qh + (size_t)(m0 + ln) * D_HEAD + dt * 32 + quad * 8);
    }

    floatx4 oacc[2][8] = {};
    float mrow[2][4], lrow[2][4];
#pragma unroll
    for (int s = 0; s < 2; ++s)
#pragma unroll
        for (int r = 0; r < 4; ++r) { mrow[s][r] = -INFINITY; lrow[s][r] = 0.f; }

    half_t* Pw = Ps + w * (16 * 72);

    for (int l0 = c * LCHUNK; l0 < (c + 1) * LCHUNK; l0 += 64) {
        __syncthreads();
        {   // stage K tile 64(l) x 128(d) into KV as [l][d] pad 136
            int lr = t >> 4, ch = t & 15;
#pragma unroll
            for (int p = 0; p < 4; ++p, lr += 16)
                *(half8*)&KV[lr * 136 + ch * 8] =
                    *(const half8*)(Kh + (size_t)(l0 + lr) * D_HEAD + ch * 8);
        }
        __syncthreads();

        // S[2][16][64] = Q K^T ; Ks fragment shared across strips
        floatx4 sacc[2][4] = {};
#pragma unroll
        for (int nt = 0; nt < 4; ++nt)
#pragma unroll
            for (int dt = 0; dt < 4; ++dt) {
                half8 b = *(half8*)&KV[(nt * 16 + ln) * 136 + dt * 32 + quad * 8];
                sacc[0][nt] = __builtin_amdgcn_mfma_f32_16x16x32_f16(qf[0][dt], b, sacc[0][nt], 0, 0, 0);
                sacc[1][nt] = __builtin_amdgcn_mfma_f32_16x16x32_f16(qf[1][dt], b, sacc[1][nt], 0, 0, 0);
            }

        // online softmax per strip (results stay in sacc registers)
        float alpha[2][4];
#pragma unroll
        for (int s = 0; s < 2; ++s)
#pragma unroll
            for (int r = 0; r < 4; ++r) {
                float mx = fmaxf(fmaxf(sacc[s][0][r], sacc[s][1][r]),
                                 fmaxf(sacc[s][2][r], sacc[s][3][r]));
#pragma unroll
                for (int msk = 8; msk; msk >>= 1) mx = fmaxf(mx, __shfl_xor(mx, msk, 16));
                float mnew = fmaxf(mrow[s][r], mx);
                alpha[s][r] = __expf(mrow[s][r] - mnew);
                mrow[s][r] = mnew;
                float psum = 0.f;
#pragma unroll
                for (int nt = 0; nt < 4; ++nt) {
                    float p = __expf(sacc[s][nt][r] - mnew);
                    sacc[s][nt][r] = p;
                    psum += p;
                }
#pragma unroll
                for (int msk = 8; msk; msk >>= 1) psum += __shfl_xor(psum, msk, 16);
                lrow[s][r] = lrow[s][r] * alpha[s][r] + psum;
            }

        __syncthreads();  // all waves done reading K from KV
        {   // stage V tile 128(d) x 64(l) into KV as [d][l] pad 72
            int dr = t >> 3, ch = t & 7;
#pragma unroll
            for (int p = 0; p < 4; ++p, dr += 32)
                *(half8*)&KV[dr * 72 + ch * 8] =
                    *(const half8*)(Vh + (size_t)dr * L_CACHE + l0 + ch * 8);
        }
        __syncthreads();

        // per strip: P -> per-wave LDS, rescale O, O += P @ V
#pragma unroll
        for (int s = 0; s < 2; ++s) {
#pragma unroll
            for (int nt = 0; nt < 4; ++nt)
#pragma unroll
                for (int r = 0; r < 4; ++r)
                    Pw[(quad * 4 + r) * 72 + nt * 16 + ln] = (half_t)sacc[s][nt][r];

#pragma unroll
            for (int nt8 = 0; nt8 < 8; ++nt8)
#pragma unroll
                for (int r = 0; r < 4; ++r)
                    oacc[s][nt8][r] *= alpha[s][r];

#pragma unroll
            for (int kt = 0; kt < 2; ++kt) {
                half8 a = *(half8*)&Pw[ln * 72 + kt * 32 + quad * 8];
#pragma unroll
                for (int nt8 = 0; nt8 < 8; ++nt8) {
                    half8 b = *(half8*)&KV[(nt8 * 16 + ln) * 72 + kt * 32 + quad * 8];
                    oacc[s][nt8] = __builtin_amdgcn_mfma_f32_16x16x32_f16(a, b, oacc[s][nt8], 0, 0, 0);
                }
            }
        }
    }

    // Opart [c][h][m][d]; stats [c][h][m]
    half_t* Oc = Opart + ((size_t)(c * H_HEADS + h) * M_TOK) * D_HEAD;
    float* ms = mstat + (size_t)(c * H_HEADS + h) * M_TOK;
    float* ls = lstat + (size_t)(c * H_HEADS + h) * M_TOK;
#pragma unroll
    for (int s = 0; s < 2; ++s) {
        int m0 = mb + s * 64 + w * 16;
#pragma unroll
        for (int nt8 = 0; nt8 < 8; ++nt8) {
            int col = nt8 * 16 + ln;
#pragma unroll
            for (int r = 0; r < 4; ++r)
                Oc[(size_t)(m0 + quad * 4 + r) * D_HEAD + col] = (half_t)oacc[s][nt8][r];
        }
        if (ln == 0) {
#pragma unroll
            for (int r = 0; r < 4; ++r) {
                ms[m0 + quad * 4 + r] = mrow[s][r];
                ls[m0 + quad * 4 + r] = lrow[s][r];
            }
        }
    }
}

// ---------------------------------------------------------------------------
// Kernel 4: combine NCHUNK fp16 partials. One wave per (h,m) row.
// ---------------------------------------------------------------------------
__global__ __launch_bounds__(256) void combine_kernel(const half_t* __restrict__ Opart,
                                                      const float* __restrict__ mstat,
                                                      const float* __restrict__ lstat,
                                                      float* __restrict__ out) {
    int gw = blockIdx.x * 4 + (threadIdx.x >> 6);
    int lane = threadIdx.x & 63;
    int h = gw >> 9, m = gw & 511;
    int d = lane * 2;

    float ms[NCHUNK];
    float mg = -INFINITY;
#pragma unroll
    for (int c = 0; c < NCHUNK; ++c) {
        ms[c] = mstat[((c * H_HEADS + h) << 9) + m];
        mg = fmaxf(mg, ms[c]);
    }
    float denom = 0.f, o0 = 0.f, o1 = 0.f;
#pragma unroll
    for (int c = 0; c < NCHUNK; ++c) {
        float e = __expf(ms[c] - mg);
        denom += lstat[((c * H_HEADS + h) << 9) + m] * e;
        const half_t* Oc = Opart + (((size_t)(c * H_HEADS + h) << 9) + m) * D_HEAD + d;
        half2_t v = *(const half2_t*)Oc;
        o0 += (float)v.x * e;
        o1 += (float)v.y * e;
    }
    float inv = 1.0f / denom;
    float* op = out + (size_t)m * N_DIM + h * D_HEAD + d;
    op[0] = o0 * inv;
    op[1] = o1 * inv;
}

// ---------------------------------------------------------------------------
extern "C" void kernel_launch(void* const* d_in, const int* in_sizes, int n_in,
                              void* d_out, int out_size, void* d_ws, size_t ws_size,
                              hipStream_t stream) {
    const float* X = (const float*)d_in[0];
    const float* W = (const float*)d_in[1];
    const float* cK = (const float*)d_in[2];
    const float* cV = (const float*)d_in[3];
    const int* Pp = (const int*)d_in[4];
    float* out = (float*)d_out;

    char* ws = (char*)d_ws;
    // workspace layout (bytes):
    //   Q16    @ 0           (2,097,152)
    //   K16    @ 2,097,152   (16,777,216)
    //   V16T   @ 18,874,368  (16,777,216)
    //   X16    @ 35,651,584  (2,097,152)
    //   W16T   @ 37,748,736  (25,165,824)  [dead after gemm_fused]
    //   Opart16@ 37,748,736  (33,554,432)  [overlays W16T]
    //   mstat  @ 71,303,168  (524,288)
    //   lstat  @ 71,827,456  (524,288)
    //   total 72,351,744
    half_t* Q16 = (half_t*)(ws + 0);
    half_t* K16 = (half_t*)(ws + 2097152);
    half_t* V16T = (half_t*)(ws + 18874368);
    half_t* X16 = (half_t*)(ws + 35651584);
    half_t* W16T = (half_t*)(ws + 37748736);
    half_t* Opart = (half_t*)(ws + 37748736);
    float* mstat = (float*)(ws + 71303168);
    float* lstat = (float*)(ws + 71827456);

    prep_kernel<<<14336, 256, 0, stream>>>(cK, cV, W, X, K16, V16T, W16T, X16);
    gemm_fused_kernel<<<dim3(48, 8), 256, 0, stream>>>(X16, W16T, Pp, Q16, K16, V16T);
    attn_partial_kernel<<<1024, 256, 0, stream>>>(Q16, K16, V16T, Opart, mstat, lstat);
    combine_kernel<<<2048, 256, 0, stream>>>(Opart, mstat, lstat, out);
}